// Round 11
// baseline (361.746 us; speedup 1.0000x reference)
//
#include <hip/hip_runtime.h>
#include <cstdint>

#define BB 8
#define NN 16384
#define CC 128
#define HEADS 2
#define HD 64
#define NK 256

// workspace offsets (in float/u32 slots)
#define OFF_CF   0          // conv B-frags 16x16x32: [ks 256][nt 8][l 64][jp 4] = 524288
#define OFF_KVF  524288     // kv B-frags 16x16x32: [ks 4][nt 16][l 64][jp 4]   = 16384
#define OFF_QF   540672     // q_w B-frags 32x32x16: [ks 8][nt 4][l 64][jp 4]   = 8192
#define OFF_PF   548864     // proj_w B-frags 32x32x16: [ks 8][nt 4][l 64][jp 4] = 8192
#define OFF_K    557056     // K f32 [bh 16][256][64] = 262144
#define OFF_V    819200     // V f32 [bh 16][256][64] = 262144
#define OFF_PART 1081344    // conv partials f32 [nq][128][2048]

typedef __attribute__((ext_vector_type(8))) __bf16 bf16x8;
typedef __attribute__((ext_vector_type(16))) float f32x16;
typedef __attribute__((ext_vector_type(4))) float f32x4;

union U4 { uint32_t u[4]; uint4 q; bf16x8 v; };

__device__ __forceinline__ uint32_t cvt_pk_bf16(float lo, float hi) {
  uint32_t r;
  asm("v_cvt_pk_bf16_f32 %0, %1, %2" : "=v"(r) : "v"(lo), "v"(hi));
  return r;
}
__device__ __forceinline__ void permswap(uint32_t& a, uint32_t& b) {
  asm("v_permlane32_swap_b32 %0, %1" : "+v"(a), "+v"(b));
}

// grid 2176 x 256 = 557056 exactly  (verbatim round-8, validated)
__global__ __launch_bounds__(256) void prep_w(
    const float* __restrict__ sr_w, const float* __restrict__ proj_w,
    const float* __restrict__ kv_w, const float* __restrict__ q_w,
    float* __restrict__ ws) {
  int tid = blockIdx.x * 256 + threadIdx.x;
  if (tid < 524288) {
    int u = tid;
    int jp = u & 3, l = (u >> 2) & 63, nt = (u >> 8) & 7, ks = u >> 11;
    int k = ks * 32 + ((l >> 4) & 3) * 8 + jp * 2;
    int o = nt * 16 + (l & 15);
    int c = k & 127, p = k >> 7;
    ((uint32_t*)(ws + OFF_CF))[u] =
        cvt_pk_bf16(sr_w[o * 8192 + c * 64 + p], sr_w[o * 8192 + (c + 1) * 64 + p]);
  } else if (tid < 540672) {
    int u = tid - 524288;
    int jp = u & 3, l = (u >> 2) & 63, nt = (u >> 8) & 15, ks = u >> 12;
    int k = ks * 32 + ((l >> 4) & 3) * 8 + jp * 2;
    int o = nt * 16 + (l & 15);
    ((uint32_t*)(ws + OFF_KVF))[u] = cvt_pk_bf16(kv_w[o * 128 + k], kv_w[o * 128 + k + 1]);
  } else if (tid < 548864) {
    int u = tid - 540672;
    int jp = u & 3, l = (u >> 2) & 63, nt = (u >> 8) & 3, ks = u >> 10;
    int k = ks * 16 + (l >> 5) * 8 + jp * 2;
    int o = nt * 32 + (l & 31);
    ((uint32_t*)(ws + OFF_QF))[u] = cvt_pk_bf16(q_w[o * 128 + k], q_w[o * 128 + k + 1]);
  } else {
    int u = tid - 548864;
    int jp = u & 3, l = (u >> 2) & 63, nt = (u >> 8) & 3, ks = u >> 10;
    int k = ks * 16 + (l >> 5) * 8 + jp * 2;
    int o = nt * 32 + (l & 31);
    ((uint32_t*)(ws + OFF_PF))[u] = cvt_pk_bf16(proj_w[o * 128 + k], proj_w[o * 128 + k + 1]);
  }
}

// Conv split-K (verbatim round 8 code; NSUB=1 instantiation added for nq=8).
template<int NSUB>
__global__ __launch_bounds__(512, 2) void conv_partial(
    const float* __restrict__ x, const uint32_t* __restrict__ cf,
    float* __restrict__ partial) {
  extern __shared__ __align__(16) char lds[];
  const int t = threadIdx.x;
  const int l = t & 63, w = t >> 6;
  const int NQ = 8 / NSUB;
  const int tile = blockIdx.x / NQ;
  const int khq  = blockIdx.x % NQ;
  const int b  = tile >> 4;
  const int ti = tile & 15;
  char* sreg = lds + w * 4096;
  const int col = l & 15, kg = (l >> 4) & 3;

  f32x4 acc[8];
  #pragma unroll
  for (int nt = 0; nt < 8; ++nt) acc[nt] = (f32x4)0.0f;

  #pragma unroll
  for (int si = 0; si < NSUB; ++si) {
    const int sub = khq * NSUB + si;
    #pragma unroll
    for (int it = 0; it < 4; ++it) {
      int flat = it * 64 + l;
      int tk = flat >> 4, c16 = flat & 15;
      const float* src = x + ((size_t)b * NN + ((ti * 8 + w) * 128 + tk * 8 + sub)) * CC + c16 * 8;
      float4 a0 = *(const float4*)(src);
      float4 a1 = *(const float4*)(src + 4);
      U4 pk;
      pk.u[0] = cvt_pk_bf16(a0.x, a0.y); pk.u[1] = cvt_pk_bf16(a0.z, a0.w);
      pk.u[2] = cvt_pk_bf16(a1.x, a1.y); pk.u[3] = cvt_pk_bf16(a1.z, a1.w);
      *(uint4*)(sreg + tk * 256 + ((c16 * 16) ^ ((tk & 7) << 4))) = pk.q;
    }
    const int ksg0 = (w * 8 + sub) * 4;
    #pragma unroll
    for (int ksl = 0; ksl < 4; ++ksl) {
      U4 a;
      a.q = *(const uint4*)(sreg + col * 256 + ((ksl * 64 + kg * 16) ^ ((col & 7) << 4)));
      #pragma unroll
      for (int nt = 0; nt < 8; ++nt) {
        U4 bf_;
        bf_.q = *(const uint4*)(cf + (((ksg0 + ksl) * 8 + nt) * 64 + l) * 4);
        acc[nt] = __builtin_amdgcn_mfma_f32_16x16x32_bf16(a.v, bf_.v, acc[nt], 0, 0, 0);
      }
    }
  }

  float* rbuf = (float*)(lds + 32768);
  if (w >= 4) {
    float* dst = rbuf + (w - 4) * 2048;
    #pragma unroll
    for (int nt = 0; nt < 8; ++nt)
      #pragma unroll
      for (int r = 0; r < 4; ++r) dst[(kg * 4 + r) * 128 + nt * 16 + col] = acc[nt][r];
  }
  __syncthreads();
  if (w < 4) {
    const float* s1 = rbuf + w * 2048;
    #pragma unroll
    for (int nt = 0; nt < 8; ++nt)
      #pragma unroll
      for (int r = 0; r < 4; ++r) acc[nt][r] += s1[(kg * 4 + r) * 128 + nt * 16 + col];
    if (w >= 2) {
      float* dst = rbuf + w * 2048;
      #pragma unroll
      for (int nt = 0; nt < 8; ++nt)
        #pragma unroll
        for (int r = 0; r < 4; ++r) dst[(kg * 4 + r) * 128 + nt * 16 + col] = acc[nt][r];
    }
  }
  __syncthreads();
  if (w < 2) {
    const float* s2 = rbuf + (w + 2) * 2048;
    #pragma unroll
    for (int nt = 0; nt < 8; ++nt)
      #pragma unroll
      for (int r = 0; r < 4; ++r) acc[nt][r] += s2[(kg * 4 + r) * 128 + nt * 16 + col];
    if (w == 1) {
      float* dst = rbuf + 2048;
      #pragma unroll
      for (int nt = 0; nt < 8; ++nt)
        #pragma unroll
        for (int r = 0; r < 4; ++r) dst[(kg * 4 + r) * 128 + nt * 16 + col] = acc[nt][r];
    }
  }
  __syncthreads();
  if (w == 0) {
    const float* s3 = rbuf + 2048;
    #pragma unroll
    for (int nt = 0; nt < 8; ++nt)
      #pragma unroll
      for (int r = 0; r < 4; ++r) {
        acc[nt][r] += s3[(kg * 4 + r) * 128 + nt * 16 + col];
        rbuf[(kg * 4 + r) * 128 + nt * 16 + col] = acc[nt][r];
      }
  }
  __syncthreads();
  float4 vv = ((const float4*)rbuf)[t];
  ((float4*)(partial + ((size_t)khq * 128 + tile) * 2048))[t] = vv;
}

// Reduce + LN + KV proj (verbatim round 8, validated).
__global__ __launch_bounds__(512) void reduce_ln_kv(
    const float* __restrict__ partial, int nq,
    const uint32_t* __restrict__ kvf, const float* __restrict__ kv_b,
    const float* __restrict__ ln_g, const float* __restrict__ ln_b,
    float* __restrict__ kbuf, float* __restrict__ vbuf) {
  __shared__ __align__(16) char abuf[4096];
  const int t = threadIdx.x;
  const int l = t & 63, w = t >> 6;
  const int tile = blockIdx.x;
  const int b = tile >> 4, nk0 = (tile & 15) * 16;

  float4 a = make_float4(0.f, 0.f, 0.f, 0.f);
  for (int i = 0; i < nq; ++i) {
    float4 p = *(const float4*)(partial + ((size_t)i * 128 + tile) * 2048 + t * 4);
    a.x += p.x; a.y += p.y; a.z += p.z; a.w += p.w;
  }
  {
    const int tk = t >> 5, j = t & 31;
    float s  = a.x + a.y + a.z + a.w;
    float ss = a.x * a.x + a.y * a.y + a.z * a.z + a.w * a.w;
    #pragma unroll
    for (int m = 16; m; m >>= 1) { s += __shfl_xor(s, m); ss += __shfl_xor(ss, m); }
    float mu  = s * 0.0078125f;
    float var = fmaxf(ss * 0.0078125f - mu * mu, 0.f);
    float rs  = rsqrtf(var + 1e-5f);
    float4 g4 = *(const float4*)(ln_g + j * 4);
    float4 b4 = *(const float4*)(ln_b + j * 4);
    float y0 = (a.x - mu) * rs * g4.x + b4.x;
    float y1 = (a.y - mu) * rs * g4.y + b4.y;
    float y2 = (a.z - mu) * rs * g4.z + b4.z;
    float y3 = (a.w - mu) * rs * g4.w + b4.w;
    *(uint2*)(abuf + tk * 256 + ((j * 8) ^ ((tk & 7) << 4))) =
        make_uint2(cvt_pk_bf16(y0, y1), cvt_pk_bf16(y2, y3));
  }
  __syncthreads();

  const int col = l & 15, kg = (l >> 4) & 3;
  f32x4 kacc[2];
  kacc[0] = (f32x4)0.0f; kacc[1] = (f32x4)0.0f;
  #pragma unroll
  for (int ks = 0; ks < 4; ++ks) {
    U4 aa;
    aa.q = *(const uint4*)(abuf + col * 256 + ((ks * 64 + kg * 16) ^ ((col & 7) << 4)));
    #pragma unroll
    for (int i = 0; i < 2; ++i) {
      int nt = w * 2 + i;
      U4 bf_;
      bf_.q = *(const uint4*)(kvf + ((ks * 16 + nt) * 64 + l) * 4);
      kacc[i] = __builtin_amdgcn_mfma_f32_16x16x32_bf16(aa.v, bf_.v, kacc[i], 0, 0, 0);
    }
  }
  #pragma unroll
  for (int i = 0; i < 2; ++i) {
    int kvo = (w * 2 + i) * 16 + col;
    float bias = kv_b[kvo];
    float* obuf = (kvo >= 128) ? vbuf : kbuf;
    int h = (kvo >> 6) & 1, d = kvo & 63;
    #pragma unroll
    for (int r = 0; r < 4; ++r) {
      int tkr = kg * 4 + r;
      obuf[(((size_t)b * HEADS + h) * NK + nk0 + tkr) * HD + d] = kacc[i][r] + bias;
    }
  }
}

// Thin MFMA GEMM (verbatim rounds 2-8, validated).
__global__ __launch_bounds__(256) void gemm128(
    const float* X, const uint32_t* __restrict__ frags,
    const float* __restrict__ bias, float scale, float* Y) {
  const int t = threadIdx.x;
  const int l = t & 63, wid = t >> 6;
  const int lq = l & 31, lh = l >> 5;
  const size_t rowbase = (size_t)blockIdx.x * 128 + wid * 32;
  const float* xrow = X + (rowbase + lq) * CC;
  f32x16 acc[4];
  #pragma unroll
  for (int nt = 0; nt < 4; ++nt) acc[nt] = (f32x16)0.0f;
  #pragma unroll
  for (int ks = 0; ks < 8; ++ks) {
    float4 a0 = *(const float4*)(xrow + ks * 16 + lh * 8);
    float4 a1 = *(const float4*)(xrow + ks * 16 + lh * 8 + 4);
    U4 af;
    af.u[0] = cvt_pk_bf16(a0.x, a0.y); af.u[1] = cvt_pk_bf16(a0.z, a0.w);
    af.u[2] = cvt_pk_bf16(a1.x, a1.y); af.u[3] = cvt_pk_bf16(a1.z, a1.w);
    #pragma unroll
    for (int nt = 0; nt < 4; ++nt) {
      U4 bf_;
      bf_.q = *(const uint4*)(frags + ((ks * 4 + nt) * 64 + l) * 4);
      acc[nt] = __builtin_amdgcn_mfma_f32_32x32x16_bf16(af.v, bf_.v, acc[nt], 0, 0, 0);
    }
  }
  #pragma unroll
  for (int nt = 0; nt < 4; ++nt) {
    int o = nt * 32 + lq;
    float bv = bias[o];
    #pragma unroll
    for (int r = 0; r < 16; ++r) {
      int m = (r & 3) + 8 * (r >> 2) + 4 * lh;
      Y[(rowbase + m) * CC + o] = (acc[nt][r] + bv) * scale;
    }
  }
}

// MFMA attention, 32KB LDS (K staged, then V^T re-staged into same buffer).
// Numerics bit-identical to round 8's attn_mfma; only V's LDS base (-32768)
// and barrier placement changed. 2048 blocks x 256 thr (4 waves).
__global__ __launch_bounds__(256, 4) void attn_mfma32(
    const float* __restrict__ qsrc, const float* __restrict__ kbuf,
    const float* __restrict__ vbuf, float* __restrict__ out) {
  __shared__ __align__(16) char lds[32768];
  const int t  = threadIdx.x;
  const int l  = t & 63, wid = t >> 6;
  const int lq = l & 31, lh = l >> 5;
  const int bh = blockIdx.x >> 7;
  const int b  = bh >> 1, h = bh & 1;
  const int qbase = (blockIdx.x & 127) * 128;

  // ---- Phase A: Q B-frags straight from global fp32 (validated) ----
  U4 qb[4];
  {
    const float* q0 = qsrc + ((size_t)b * NN + qbase + wid * 32 + lq) * CC + h * 64;
    #pragma unroll
    for (int kg = 0; kg < 4; ++kg) {
      float4 x0 = *(const float4*)(q0 + kg * 16 + lh * 8);
      float4 x1 = *(const float4*)(q0 + kg * 16 + lh * 8 + 4);
      qb[kg].u[0] = cvt_pk_bf16(x0.x, x0.y); qb[kg].u[1] = cvt_pk_bf16(x0.z, x0.w);
      qb[kg].u[2] = cvt_pk_bf16(x1.x, x1.y); qb[kg].u[3] = cvt_pk_bf16(x1.z, x1.w);
    }
  }

  // ---- Phase B-K: stage K [256][64] swizzled bf16 (validated code) ----
  {
    const float* kb = kbuf + (size_t)bh * NK * HD;
    #pragma unroll
    for (int it = 0; it < 16; ++it) {
      int flat = it * 256 + t;
      int key = flat >> 4, j = flat & 15;
      float4 kv = *(const float4*)(kb + key * HD + j * 4);
      int byte = (key * 128 + j * 8) ^ ((key & 7) << 4);
      *(uint2*)(lds + byte) = make_uint2(cvt_pk_bf16(kv.x, kv.y), cvt_pk_bf16(kv.z, kv.w));
    }
  }
  __syncthreads();

  // ---- Phase C: S^T = K · Q^T (validated) ----
  f32x16 p[8];
  #pragma unroll
  for (int kt = 0; kt < 8; ++kt) p[kt] = (f32x16)0.0f;
  #pragma unroll
  for (int kt = 0; kt < 8; ++kt) {
    const int key = kt * 32 + lq;
    #pragma unroll
    for (int kg = 0; kg < 4; ++kg) {
      U4 a;
      int byte = (key * 128 + kg * 32 + lh * 16) ^ ((key & 7) << 4);
      a.q = *(const uint4*)(lds + byte);
      p[kt] = __builtin_amdgcn_mfma_f32_32x32x16_bf16(a.v, qb[kg].v, p[kt], 0, 0, 0);
    }
  }
  __syncthreads();   // all K reads complete before V overwrites the buffer

  // ---- Phase B-V: stage V^T [64][256] swizzled bf16 at base 0 ----
  {
    const float* vb = vbuf + (size_t)bh * NK * HD;
    int d = t & 63, kb4 = t >> 6;
    #pragma unroll
    for (int k0 = 0; k0 < 64; k0 += 4) {
      int k = kb4 * 64 + k0;
      float v0 = vb[(k + 0) * HD + d], v1 = vb[(k + 1) * HD + d];
      float v2 = vb[(k + 2) * HD + d], v3 = vb[(k + 3) * HD + d];
      int byte = (d * 512 + k * 2) ^ ((d & 7) << 4);
      *(uint2*)(lds + byte) = make_uint2(cvt_pk_bf16(v0, v1), cvt_pk_bf16(v2, v3));
    }
  }

  // ---- Phase D: softmax (register-only; overlaps V staging) ----
  float mx = -1e30f;
  #pragma unroll
  for (int kt = 0; kt < 8; ++kt)
    #pragma unroll
    for (int i = 0; i < 16; ++i) mx = fmaxf(mx, p[kt][i]);
  mx = fmaxf(mx, __shfl_xor(mx, 32));
  float sum = 0.f;
  #pragma unroll
  for (int kt = 0; kt < 8; ++kt)
    #pragma unroll
    for (int i = 0; i < 16; ++i) { float e = __expf(p[kt][i] - mx); p[kt][i] = e; sum += e; }
  sum += __shfl_xor(sum, 32);
  const float inv = 1.f / sum;
  #pragma unroll
  for (int kt = 0; kt < 8; ++kt)
    #pragma unroll
    for (int i = 0; i < 16; ++i) p[kt][i] *= inv;
  __syncthreads();   // V fully staged

  // ---- Phase E: O = P · V (validated; offsets minus 32768) ----
  f32x16 oacc0 = (f32x16)0.0f, oacc1 = (f32x16)0.0f;
  #pragma unroll
  for (int kt = 0; kt < 8; ++kt) {
    uint32_t x0 = cvt_pk_bf16(p[kt][0],  p[kt][1]);
    uint32_t x1 = cvt_pk_bf16(p[kt][2],  p[kt][3]);
    uint32_t y0 = cvt_pk_bf16(p[kt][4],  p[kt][5]);
    uint32_t y1 = cvt_pk_bf16(p[kt][6],  p[kt][7]);
    permswap(x0, y0); permswap(x1, y1);
    U4 pa0; pa0.u[0] = x0; pa0.u[1] = x1; pa0.u[2] = y0; pa0.u[3] = y1;
    uint32_t x2 = cvt_pk_bf16(p[kt][8],  p[kt][9]);
    uint32_t x3 = cvt_pk_bf16(p[kt][10], p[kt][11]);
    uint32_t y2 = cvt_pk_bf16(p[kt][12], p[kt][13]);
    uint32_t y3 = cvt_pk_bf16(p[kt][14], p[kt][15]);
    permswap(x2, y2); permswap(x3, y3);
    U4 pa1; pa1.u[0] = x2; pa1.u[1] = x3; pa1.u[2] = y2; pa1.u[3] = y3;
    #pragma unroll
    for (int dt = 0; dt < 2; ++dt) {
      int d = dt * 32 + lq;
      U4 vb0, vb1;
      int byte0 = (d * 512 + kt * 64 + lh * 16) ^ ((d & 7) << 4);
      int byte1 = (d * 512 + kt * 64 + 32 + lh * 16) ^ ((d & 7) << 4);
      vb0.q = *(const uint4*)(lds + byte0);
      vb1.q = *(const uint4*)(lds + byte1);
      f32x16& oa = dt ? oacc1 : oacc0;
      oa = __builtin_amdgcn_mfma_f32_32x32x16_bf16(pa0.v, vb0.v, oa, 0, 0, 0);
      oa = __builtin_amdgcn_mfma_f32_32x32x16_bf16(pa1.v, vb1.v, oa, 0, 0, 0);
    }
  }

  // ---- Phase F: coalesced store (validated) ----
  float* ob = out + ((size_t)b * NN + qbase + wid * 32) * CC + h * 64;
  #pragma unroll
  for (int reg = 0; reg < 16; ++reg) {
    int q = (reg & 3) + 8 * (reg >> 2) + 4 * lh;
    ob[q * CC + lq]      = oacc0[reg];
    ob[q * CC + 32 + lq] = oacc1[reg];
  }
}

extern "C" void kernel_launch(void* const* d_in, const int* in_sizes, int n_in,
                              void* d_out, int out_size, void* d_ws, size_t ws_size,
                              hipStream_t stream) {
  const float* x      = (const float*)d_in[0];
  const float* q_w    = (const float*)d_in[3];
  const float* q_b    = (const float*)d_in[4];
  const float* kv_w   = (const float*)d_in[5];
  const float* kv_b   = (const float*)d_in[6];
  const float* sr_w   = (const float*)d_in[7];
  const float* ln_g   = (const float*)d_in[8];
  const float* ln_b   = (const float*)d_in[9];
  const float* proj_w = (const float*)d_in[10];
  const float* proj_b = (const float*)d_in[11];
  float* out = (float*)d_out;
  float* ws  = (float*)d_ws;

  prep_w<<<dim3(2176), dim3(256), 0, stream>>>(sr_w, proj_w, kv_w, q_w, ws);

  int nq = 1;
  if (ws_size >= (size_t)(OFF_PART + 8 * 262144) * 4) nq = 8;
  else if (ws_size >= (size_t)(OFF_PART + 4 * 262144) * 4) nq = 4;
  else if (ws_size >= (size_t)(OFF_PART + 2 * 262144) * 4) nq = 2;

  const uint32_t* cf = (const uint32_t*)(ws + OFF_CF);
  float* part = ws + OFF_PART;
  if (nq == 8)
    conv_partial<1><<<dim3(1024), dim3(512), 65536, stream>>>(x, cf, part);
  else if (nq == 4)
    conv_partial<2><<<dim3(512), dim3(512), 65536, stream>>>(x, cf, part);
  else if (nq == 2)
    conv_partial<4><<<dim3(256), dim3(512), 65536, stream>>>(x, cf, part);
  else
    conv_partial<8><<<dim3(128), dim3(512), 65536, stream>>>(x, cf, part);

  reduce_ln_kv<<<dim3(128), dim3(512), 0, stream>>>(
      part, nq, (const uint32_t*)(ws + OFF_KVF), kv_b, ln_g, ln_b,
      ws + OFF_K, ws + OFF_V);
  gemm128<<<dim3(1024), dim3(256), 0, stream>>>(
      x, (const uint32_t*)(ws + OFF_QF), q_b, 0.125f, out);
  attn_mfma32<<<dim3(2048), dim3(256), 0, stream>>>(
      out, ws + OFF_K, ws + OFF_V, out);
  gemm128<<<dim3(1024), dim3(256), 0, stream>>>(
      out, (const uint32_t*)(ws + OFF_PF), proj_b, 1.0f, out);
}

// Round 12
// 144.175 us; speedup vs baseline: 2.5091x; 2.5091x over previous
//
#include <hip/hip_runtime.h>
#include <cstdint>

#define BB 8
#define NN 16384
#define CC 128
#define HEADS 2
#define HD 64
#define NK 256

// workspace offsets (in float/u32 slots)
#define OFF_CF   0          // conv B-frags 16x16x32: [ks 256][nt 8][l 64][jp 4] = 524288
#define OFF_KVF  524288     // kv B-frags 16x16x32: [ks 4][nt 16][l 64][jp 4]   = 16384
#define OFF_QF   540672     // q_w B-frags 32x32x16: [ks 8][nt 4][l 64][jp 4]   = 8192
#define OFF_PF   548864     // proj_w B-frags 32x32x16: [ks 8][nt 4][l 64][jp 4] = 8192
#define OFF_K    557056     // K f32 [bh 16][256][64] = 262144
#define OFF_V    819200     // V f32 [bh 16][256][64] = 262144
#define OFF_PART 1081344    // conv partials f32 [nq][128][2048]

typedef __attribute__((ext_vector_type(8))) __bf16 bf16x8;
typedef __attribute__((ext_vector_type(16))) float f32x16;
typedef __attribute__((ext_vector_type(4))) float f32x4;

union U4 { uint32_t u[4]; uint4 q; bf16x8 v; };

__device__ __forceinline__ uint32_t cvt_pk_bf16(float lo, float hi) {
  uint32_t r;
  asm("v_cvt_pk_bf16_f32 %0, %1, %2" : "=v"(r) : "v"(lo), "v"(hi));
  return r;
}
__device__ __forceinline__ void permswap(uint32_t& a, uint32_t& b) {
  asm("v_permlane32_swap_b32 %0, %1" : "+v"(a), "+v"(b));
}

// grid 2176 x 256 = 557056 exactly  (verbatim round-8, validated)
__global__ __launch_bounds__(256) void prep_w(
    const float* __restrict__ sr_w, const float* __restrict__ proj_w,
    const float* __restrict__ kv_w, const float* __restrict__ q_w,
    float* __restrict__ ws) {
  int tid = blockIdx.x * 256 + threadIdx.x;
  if (tid < 524288) {
    int u = tid;
    int jp = u & 3, l = (u >> 2) & 63, nt = (u >> 8) & 7, ks = u >> 11;
    int k = ks * 32 + ((l >> 4) & 3) * 8 + jp * 2;
    int o = nt * 16 + (l & 15);
    int c = k & 127, p = k >> 7;
    ((uint32_t*)(ws + OFF_CF))[u] =
        cvt_pk_bf16(sr_w[o * 8192 + c * 64 + p], sr_w[o * 8192 + (c + 1) * 64 + p]);
  } else if (tid < 540672) {
    int u = tid - 524288;
    int jp = u & 3, l = (u >> 2) & 63, nt = (u >> 8) & 15, ks = u >> 12;
    int k = ks * 32 + ((l >> 4) & 3) * 8 + jp * 2;
    int o = nt * 16 + (l & 15);
    ((uint32_t*)(ws + OFF_KVF))[u] = cvt_pk_bf16(kv_w[o * 128 + k], kv_w[o * 128 + k + 1]);
  } else if (tid < 548864) {
    int u = tid - 540672;
    int jp = u & 3, l = (u >> 2) & 63, nt = (u >> 8) & 3, ks = u >> 10;
    int k = ks * 16 + (l >> 5) * 8 + jp * 2;
    int o = nt * 32 + (l & 31);
    ((uint32_t*)(ws + OFF_QF))[u] = cvt_pk_bf16(q_w[o * 128 + k], q_w[o * 128 + k + 1]);
  } else {
    int u = tid - 548864;
    int jp = u & 3, l = (u >> 2) & 63, nt = (u >> 8) & 3, ks = u >> 10;
    int k = ks * 16 + (l >> 5) * 8 + jp * 2;
    int o = nt * 32 + (l & 31);
    ((uint32_t*)(ws + OFF_PF))[u] = cvt_pk_bf16(proj_w[o * 128 + k], proj_w[o * 128 + k + 1]);
  }
}

// Conv split-K (verbatim round 8/11, validated).
template<int NSUB>
__global__ __launch_bounds__(512, 2) void conv_partial(
    const float* __restrict__ x, const uint32_t* __restrict__ cf,
    float* __restrict__ partial) {
  extern __shared__ __align__(16) char lds[];
  const int t = threadIdx.x;
  const int l = t & 63, w = t >> 6;
  const int NQ = 8 / NSUB;
  const int tile = blockIdx.x / NQ;
  const int khq  = blockIdx.x % NQ;
  const int b  = tile >> 4;
  const int ti = tile & 15;
  char* sreg = lds + w * 4096;
  const int col = l & 15, kg = (l >> 4) & 3;

  f32x4 acc[8];
  #pragma unroll
  for (int nt = 0; nt < 8; ++nt) acc[nt] = (f32x4)0.0f;

  #pragma unroll
  for (int si = 0; si < NSUB; ++si) {
    const int sub = khq * NSUB + si;
    #pragma unroll
    for (int it = 0; it < 4; ++it) {
      int flat = it * 64 + l;
      int tk = flat >> 4, c16 = flat & 15;
      const float* src = x + ((size_t)b * NN + ((ti * 8 + w) * 128 + tk * 8 + sub)) * CC + c16 * 8;
      float4 a0 = *(const float4*)(src);
      float4 a1 = *(const float4*)(src + 4);
      U4 pk;
      pk.u[0] = cvt_pk_bf16(a0.x, a0.y); pk.u[1] = cvt_pk_bf16(a0.z, a0.w);
      pk.u[2] = cvt_pk_bf16(a1.x, a1.y); pk.u[3] = cvt_pk_bf16(a1.z, a1.w);
      *(uint4*)(sreg + tk * 256 + ((c16 * 16) ^ ((tk & 7) << 4))) = pk.q;
    }
    const int ksg0 = (w * 8 + sub) * 4;
    #pragma unroll
    for (int ksl = 0; ksl < 4; ++ksl) {
      U4 a;
      a.q = *(const uint4*)(sreg + col * 256 + ((ksl * 64 + kg * 16) ^ ((col & 7) << 4)));
      #pragma unroll
      for (int nt = 0; nt < 8; ++nt) {
        U4 bf_;
        bf_.q = *(const uint4*)(cf + (((ksg0 + ksl) * 8 + nt) * 64 + l) * 4);
        acc[nt] = __builtin_amdgcn_mfma_f32_16x16x32_bf16(a.v, bf_.v, acc[nt], 0, 0, 0);
      }
    }
  }

  float* rbuf = (float*)(lds + 32768);
  if (w >= 4) {
    float* dst = rbuf + (w - 4) * 2048;
    #pragma unroll
    for (int nt = 0; nt < 8; ++nt)
      #pragma unroll
      for (int r = 0; r < 4; ++r) dst[(kg * 4 + r) * 128 + nt * 16 + col] = acc[nt][r];
  }
  __syncthreads();
  if (w < 4) {
    const float* s1 = rbuf + w * 2048;
    #pragma unroll
    for (int nt = 0; nt < 8; ++nt)
      #pragma unroll
      for (int r = 0; r < 4; ++r) acc[nt][r] += s1[(kg * 4 + r) * 128 + nt * 16 + col];
    if (w >= 2) {
      float* dst = rbuf + w * 2048;
      #pragma unroll
      for (int nt = 0; nt < 8; ++nt)
        #pragma unroll
        for (int r = 0; r < 4; ++r) dst[(kg * 4 + r) * 128 + nt * 16 + col] = acc[nt][r];
    }
  }
  __syncthreads();
  if (w < 2) {
    const float* s2 = rbuf + (w + 2) * 2048;
    #pragma unroll
    for (int nt = 0; nt < 8; ++nt)
      #pragma unroll
      for (int r = 0; r < 4; ++r) acc[nt][r] += s2[(kg * 4 + r) * 128 + nt * 16 + col];
    if (w == 1) {
      float* dst = rbuf + 2048;
      #pragma unroll
      for (int nt = 0; nt < 8; ++nt)
        #pragma unroll
        for (int r = 0; r < 4; ++r) dst[(kg * 4 + r) * 128 + nt * 16 + col] = acc[nt][r];
    }
  }
  __syncthreads();
  if (w == 0) {
    const float* s3 = rbuf + 2048;
    #pragma unroll
    for (int nt = 0; nt < 8; ++nt)
      #pragma unroll
      for (int r = 0; r < 4; ++r) {
        acc[nt][r] += s3[(kg * 4 + r) * 128 + nt * 16 + col];
        rbuf[(kg * 4 + r) * 128 + nt * 16 + col] = acc[nt][r];
      }
  }
  __syncthreads();
  float4 vv = ((const float4*)rbuf)[t];
  ((float4*)(partial + ((size_t)khq * 128 + tile) * 2048))[t] = vv;
}

// Reduce + LN + KV proj (verbatim round 8, validated).
__global__ __launch_bounds__(512) void reduce_ln_kv(
    const float* __restrict__ partial, int nq,
    const uint32_t* __restrict__ kvf, const float* __restrict__ kv_b,
    const float* __restrict__ ln_g, const float* __restrict__ ln_b,
    float* __restrict__ kbuf, float* __restrict__ vbuf) {
  __shared__ __align__(16) char abuf[4096];
  const int t = threadIdx.x;
  const int l = t & 63, w = t >> 6;
  const int tile = blockIdx.x;
  const int b = tile >> 4, nk0 = (tile & 15) * 16;

  float4 a = make_float4(0.f, 0.f, 0.f, 0.f);
  for (int i = 0; i < nq; ++i) {
    float4 p = *(const float4*)(partial + ((size_t)i * 128 + tile) * 2048 + t * 4);
    a.x += p.x; a.y += p.y; a.z += p.z; a.w += p.w;
  }
  {
    const int tk = t >> 5, j = t & 31;
    float s  = a.x + a.y + a.z + a.w;
    float ss = a.x * a.x + a.y * a.y + a.z * a.z + a.w * a.w;
    #pragma unroll
    for (int m = 16; m; m >>= 1) { s += __shfl_xor(s, m); ss += __shfl_xor(ss, m); }
    float mu  = s * 0.0078125f;
    float var = fmaxf(ss * 0.0078125f - mu * mu, 0.f);
    float rs  = rsqrtf(var + 1e-5f);
    float4 g4 = *(const float4*)(ln_g + j * 4);
    float4 b4 = *(const float4*)(ln_b + j * 4);
    float y0 = (a.x - mu) * rs * g4.x + b4.x;
    float y1 = (a.y - mu) * rs * g4.y + b4.y;
    float y2 = (a.z - mu) * rs * g4.z + b4.z;
    float y3 = (a.w - mu) * rs * g4.w + b4.w;
    *(uint2*)(abuf + tk * 256 + ((j * 8) ^ ((tk & 7) << 4))) =
        make_uint2(cvt_pk_bf16(y0, y1), cvt_pk_bf16(y2, y3));
  }
  __syncthreads();

  const int col = l & 15, kg = (l >> 4) & 3;
  f32x4 kacc[2];
  kacc[0] = (f32x4)0.0f; kacc[1] = (f32x4)0.0f;
  #pragma unroll
  for (int ks = 0; ks < 4; ++ks) {
    U4 aa;
    aa.q = *(const uint4*)(abuf + col * 256 + ((ks * 64 + kg * 16) ^ ((col & 7) << 4)));
    #pragma unroll
    for (int i = 0; i < 2; ++i) {
      int nt = w * 2 + i;
      U4 bf_;
      bf_.q = *(const uint4*)(kvf + ((ks * 16 + nt) * 64 + l) * 4);
      kacc[i] = __builtin_amdgcn_mfma_f32_16x16x32_bf16(aa.v, bf_.v, kacc[i], 0, 0, 0);
    }
  }
  #pragma unroll
  for (int i = 0; i < 2; ++i) {
    int kvo = (w * 2 + i) * 16 + col;
    float bias = kv_b[kvo];
    float* obuf = (kvo >= 128) ? vbuf : kbuf;
    int h = (kvo >> 6) & 1, d = kvo & 63;
    #pragma unroll
    for (int r = 0; r < 4; ++r) {
      int tkr = kg * 4 + r;
      obuf[(((size_t)b * HEADS + h) * NK + nk0 + tkr) * HD + d] = kacc[i][r] + bias;
    }
  }
}

// Thin MFMA GEMM (verbatim rounds 2-8, validated).
__global__ __launch_bounds__(256) void gemm128(
    const float* X, const uint32_t* __restrict__ frags,
    const float* __restrict__ bias, float scale, float* Y) {
  const int t = threadIdx.x;
  const int l = t & 63, wid = t >> 6;
  const int lq = l & 31, lh = l >> 5;
  const size_t rowbase = (size_t)blockIdx.x * 128 + wid * 32;
  const float* xrow = X + (rowbase + lq) * CC;
  f32x16 acc[4];
  #pragma unroll
  for (int nt = 0; nt < 4; ++nt) acc[nt] = (f32x16)0.0f;
  #pragma unroll
  for (int ks = 0; ks < 8; ++ks) {
    float4 a0 = *(const float4*)(xrow + ks * 16 + lh * 8);
    float4 a1 = *(const float4*)(xrow + ks * 16 + lh * 8 + 4);
    U4 af;
    af.u[0] = cvt_pk_bf16(a0.x, a0.y); af.u[1] = cvt_pk_bf16(a0.z, a0.w);
    af.u[2] = cvt_pk_bf16(a1.x, a1.y); af.u[3] = cvt_pk_bf16(a1.z, a1.w);
    #pragma unroll
    for (int nt = 0; nt < 4; ++nt) {
      U4 bf_;
      bf_.q = *(const uint4*)(frags + ((ks * 4 + nt) * 64 + l) * 4);
      acc[nt] = __builtin_amdgcn_mfma_f32_32x32x16_bf16(af.v, bf_.v, acc[nt], 0, 0, 0);
    }
  }
  #pragma unroll
  for (int nt = 0; nt < 4; ++nt) {
    int o = nt * 32 + lq;
    float bv = bias[o];
    #pragma unroll
    for (int r = 0; r < 16; ++r) {
      int m = (r & 3) + 8 * (r >> 2) + 4 * lh;
      Y[(rowbase + m) * CC + o] = (acc[nt][r] + bv) * scale;
    }
  }
}

// MFMA attention, 32KB LDS (K staged, then V^T re-staged into same buffer).
// Validated in round 11 (absmax 9.155e-5). launch_bounds back to (256,2):
// the ~210-reg live state (p[8]+oacc+qb) needs the 256-reg budget; (256,4)
// forced a 128-reg cap -> 1GB of scratch spill traffic (R11 counters).
__global__ __launch_bounds__(256, 2) void attn_mfma32(
    const float* __restrict__ qsrc, const float* __restrict__ kbuf,
    const float* __restrict__ vbuf, float* __restrict__ out) {
  __shared__ __align__(16) char lds[32768];
  const int t  = threadIdx.x;
  const int l  = t & 63, wid = t >> 6;
  const int lq = l & 31, lh = l >> 5;
  const int bh = blockIdx.x >> 7;
  const int b  = bh >> 1, h = bh & 1;
  const int qbase = (blockIdx.x & 127) * 128;

  // ---- Phase A: Q B-frags straight from global fp32 (validated) ----
  U4 qb[4];
  {
    const float* q0 = qsrc + ((size_t)b * NN + qbase + wid * 32 + lq) * CC + h * 64;
    #pragma unroll
    for (int kg = 0; kg < 4; ++kg) {
      float4 x0 = *(const float4*)(q0 + kg * 16 + lh * 8);
      float4 x1 = *(const float4*)(q0 + kg * 16 + lh * 8 + 4);
      qb[kg].u[0] = cvt_pk_bf16(x0.x, x0.y); qb[kg].u[1] = cvt_pk_bf16(x0.z, x0.w);
      qb[kg].u[2] = cvt_pk_bf16(x1.x, x1.y); qb[kg].u[3] = cvt_pk_bf16(x1.z, x1.w);
    }
  }

  // ---- Phase B-K: stage K [256][64] swizzled bf16 (validated) ----
  {
    const float* kb = kbuf + (size_t)bh * NK * HD;
    #pragma unroll
    for (int it = 0; it < 16; ++it) {
      int flat = it * 256 + t;
      int key = flat >> 4, j = flat & 15;
      float4 kv = *(const float4*)(kb + key * HD + j * 4);
      int byte = (key * 128 + j * 8) ^ ((key & 7) << 4);
      *(uint2*)(lds + byte) = make_uint2(cvt_pk_bf16(kv.x, kv.y), cvt_pk_bf16(kv.z, kv.w));
    }
  }
  __syncthreads();

  // ---- Phase C: S^T = K · Q^T (validated) ----
  f32x16 p[8];
  #pragma unroll
  for (int kt = 0; kt < 8; ++kt) p[kt] = (f32x16)0.0f;
  #pragma unroll
  for (int kt = 0; kt < 8; ++kt) {
    const int key = kt * 32 + lq;
    #pragma unroll
    for (int kg = 0; kg < 4; ++kg) {
      U4 a;
      int byte = (key * 128 + kg * 32 + lh * 16) ^ ((key & 7) << 4);
      a.q = *(const uint4*)(lds + byte);
      p[kt] = __builtin_amdgcn_mfma_f32_32x32x16_bf16(a.v, qb[kg].v, p[kt], 0, 0, 0);
    }
  }
  __syncthreads();   // all K reads complete before V overwrites the buffer

  // ---- Phase B-V: stage V^T [64][256] swizzled bf16 at base 0 ----
  {
    const float* vb = vbuf + (size_t)bh * NK * HD;
    int d = t & 63, kb4 = t >> 6;
    #pragma unroll
    for (int k0 = 0; k0 < 64; k0 += 4) {
      int k = kb4 * 64 + k0;
      float v0 = vb[(k + 0) * HD + d], v1 = vb[(k + 1) * HD + d];
      float v2 = vb[(k + 2) * HD + d], v3 = vb[(k + 3) * HD + d];
      int byte = (d * 512 + k * 2) ^ ((d & 7) << 4);
      *(uint2*)(lds + byte) = make_uint2(cvt_pk_bf16(v0, v1), cvt_pk_bf16(v2, v3));
    }
  }

  // ---- Phase D: softmax (register-only; overlaps V staging) ----
  float mx = -1e30f;
  #pragma unroll
  for (int kt = 0; kt < 8; ++kt)
    #pragma unroll
    for (int i = 0; i < 16; ++i) mx = fmaxf(mx, p[kt][i]);
  mx = fmaxf(mx, __shfl_xor(mx, 32));
  float sum = 0.f;
  #pragma unroll
  for (int kt = 0; kt < 8; ++kt)
    #pragma unroll
    for (int i = 0; i < 16; ++i) { float e = __expf(p[kt][i] - mx); p[kt][i] = e; sum += e; }
  sum += __shfl_xor(sum, 32);
  const float inv = 1.f / sum;
  #pragma unroll
  for (int kt = 0; kt < 8; ++kt)
    #pragma unroll
    for (int i = 0; i < 16; ++i) p[kt][i] *= inv;
  __syncthreads();   // V fully staged

  // ---- Phase E: O = P · V (validated) ----
  f32x16 oacc0 = (f32x16)0.0f, oacc1 = (f32x16)0.0f;
  #pragma unroll
  for (int kt = 0; kt < 8; ++kt) {
    uint32_t x0 = cvt_pk_bf16(p[kt][0],  p[kt][1]);
    uint32_t x1 = cvt_pk_bf16(p[kt][2],  p[kt][3]);
    uint32_t y0 = cvt_pk_bf16(p[kt][4],  p[kt][5]);
    uint32_t y1 = cvt_pk_bf16(p[kt][6],  p[kt][7]);
    permswap(x0, y0); permswap(x1, y1);
    U4 pa0; pa0.u[0] = x0; pa0.u[1] = x1; pa0.u[2] = y0; pa0.u[3] = y1;
    uint32_t x2 = cvt_pk_bf16(p[kt][8],  p[kt][9]);
    uint32_t x3 = cvt_pk_bf16(p[kt][10], p[kt][11]);
    uint32_t y2 = cvt_pk_bf16(p[kt][12], p[kt][13]);
    uint32_t y3 = cvt_pk_bf16(p[kt][14], p[kt][15]);
    permswap(x2, y2); permswap(x3, y3);
    U4 pa1; pa1.u[0] = x2; pa1.u[1] = x3; pa1.u[2] = y2; pa1.u[3] = y3;
    #pragma unroll
    for (int dt = 0; dt < 2; ++dt) {
      int d = dt * 32 + lq;
      U4 vb0, vb1;
      int byte0 = (d * 512 + kt * 64 + lh * 16) ^ ((d & 7) << 4);
      int byte1 = (d * 512 + kt * 64 + 32 + lh * 16) ^ ((d & 7) << 4);
      vb0.q = *(const uint4*)(lds + byte0);
      vb1.q = *(const uint4*)(lds + byte1);
      f32x16& oa = dt ? oacc1 : oacc0;
      oa = __builtin_amdgcn_mfma_f32_32x32x16_bf16(pa0.v, vb0.v, oa, 0, 0, 0);
      oa = __builtin_amdgcn_mfma_f32_32x32x16_bf16(pa1.v, vb1.v, oa, 0, 0, 0);
    }
  }

  // ---- Phase F: coalesced store (validated) ----
  float* ob = out + ((size_t)b * NN + qbase + wid * 32) * CC + h * 64;
  #pragma unroll
  for (int reg = 0; reg < 16; ++reg) {
    int q = (reg & 3) + 8 * (reg >> 2) + 4 * lh;
    ob[q * CC + lq]      = oacc0[reg];
    ob[q * CC + 32 + lq] = oacc1[reg];
  }
}

extern "C" void kernel_launch(void* const* d_in, const int* in_sizes, int n_in,
                              void* d_out, int out_size, void* d_ws, size_t ws_size,
                              hipStream_t stream) {
  const float* x      = (const float*)d_in[0];
  const float* q_w    = (const float*)d_in[3];
  const float* q_b    = (const float*)d_in[4];
  const float* kv_w   = (const float*)d_in[5];
  const float* kv_b   = (const float*)d_in[6];
  const float* sr_w   = (const float*)d_in[7];
  const float* ln_g   = (const float*)d_in[8];
  const float* ln_b   = (const float*)d_in[9];
  const float* proj_w = (const float*)d_in[10];
  const float* proj_b = (const float*)d_in[11];
  float* out = (float*)d_out;
  float* ws  = (float*)d_ws;

  prep_w<<<dim3(2176), dim3(256), 0, stream>>>(sr_w, proj_w, kv_w, q_w, ws);

  int nq = 1;
  if (ws_size >= (size_t)(OFF_PART + 8 * 262144) * 4) nq = 8;
  else if (ws_size >= (size_t)(OFF_PART + 4 * 262144) * 4) nq = 4;
  else if (ws_size >= (size_t)(OFF_PART + 2 * 262144) * 4) nq = 2;

  const uint32_t* cf = (const uint32_t*)(ws + OFF_CF);
  float* part = ws + OFF_PART;
  if (nq == 8)
    conv_partial<1><<<dim3(1024), dim3(512), 65536, stream>>>(x, cf, part);
  else if (nq == 4)
    conv_partial<2><<<dim3(512), dim3(512), 65536, stream>>>(x, cf, part);
  else if (nq == 2)
    conv_partial<4><<<dim3(256), dim3(512), 65536, stream>>>(x, cf, part);
  else
    conv_partial<8><<<dim3(128), dim3(512), 65536, stream>>>(x, cf, part);

  reduce_ln_kv<<<dim3(128), dim3(512), 0, stream>>>(
      part, nq, (const uint32_t*)(ws + OFF_KVF), kv_b, ln_g, ln_b,
      ws + OFF_K, ws + OFF_V);
  gemm128<<<dim3(1024), dim3(256), 0, stream>>>(
      x, (const uint32_t*)(ws + OFF_QF), q_b, 0.125f, out);
  attn_mfma32<<<dim3(2048), dim3(256), 0, stream>>>(
      out, ws + OFF_K, ws + OFF_V, out);
  gemm128<<<dim3(1024), dim3(256), 0, stream>>>(
      out, (const uint32_t*)(ws + OFF_PF), proj_b, 1.0f, out);
}

// Round 13
// 130.030 us; speedup vs baseline: 2.7820x; 1.1088x over previous
//
#include <hip/hip_runtime.h>
#include <cstdint>

#define BB 8
#define NN 16384
#define CC 128
#define HEADS 2
#define HD 64
#define NK 256

// workspace offsets (in float/u32 slots)
#define OFF_CF   0          // conv B-frags 16x16x32: [ks 256][nt 8][l 64][jp 4] = 524288
#define OFF_KVF  524288     // kv B-frags 16x16x32: [ks 4][nt 16][l 64][jp 4]   = 16384
#define OFF_QF   540672     // q_w B-frags 32x32x16: [ks 8][nt 4][l 64][jp 4]   = 8192
#define OFF_PF   548864     // proj_w B-frags 32x32x16: [ks 8][nt 4][l 64][jp 4] = 8192
#define OFF_K    557056     // K f32 [bh 16][256][64] = 262144
#define OFF_V    819200     // V f32 [bh 16][256][64] = 262144
#define OFF_PART 1081344    // conv partials f32 [nq][128][2048]

typedef __attribute__((ext_vector_type(8))) __bf16 bf16x8;
typedef __attribute__((ext_vector_type(16))) float f32x16;
typedef __attribute__((ext_vector_type(4))) float f32x4;

union U4 { uint32_t u[4]; uint4 q; bf16x8 v; };

__device__ __forceinline__ uint32_t cvt_pk_bf16(float lo, float hi) {
  uint32_t r;
  asm("v_cvt_pk_bf16_f32 %0, %1, %2" : "=v"(r) : "v"(lo), "v"(hi));
  return r;
}
__device__ __forceinline__ void permswap(uint32_t& a, uint32_t& b) {
  asm("v_permlane32_swap_b32 %0, %1" : "+v"(a), "+v"(b));
}

// grid 2176 x 256 = 557056 exactly  (verbatim round-8, validated)
__global__ __launch_bounds__(256) void prep_w(
    const float* __restrict__ sr_w, const float* __restrict__ proj_w,
    const float* __restrict__ kv_w, const float* __restrict__ q_w,
    float* __restrict__ ws) {
  int tid = blockIdx.x * 256 + threadIdx.x;
  if (tid < 524288) {
    int u = tid;
    int jp = u & 3, l = (u >> 2) & 63, nt = (u >> 8) & 7, ks = u >> 11;
    int k = ks * 32 + ((l >> 4) & 3) * 8 + jp * 2;
    int o = nt * 16 + (l & 15);
    int c = k & 127, p = k >> 7;
    ((uint32_t*)(ws + OFF_CF))[u] =
        cvt_pk_bf16(sr_w[o * 8192 + c * 64 + p], sr_w[o * 8192 + (c + 1) * 64 + p]);
  } else if (tid < 540672) {
    int u = tid - 524288;
    int jp = u & 3, l = (u >> 2) & 63, nt = (u >> 8) & 15, ks = u >> 12;
    int k = ks * 32 + ((l >> 4) & 3) * 8 + jp * 2;
    int o = nt * 16 + (l & 15);
    ((uint32_t*)(ws + OFF_KVF))[u] = cvt_pk_bf16(kv_w[o * 128 + k], kv_w[o * 128 + k + 1]);
  } else if (tid < 548864) {
    int u = tid - 540672;
    int jp = u & 3, l = (u >> 2) & 63, nt = (u >> 8) & 3, ks = u >> 10;
    int k = ks * 16 + (l >> 5) * 8 + jp * 2;
    int o = nt * 32 + (l & 31);
    ((uint32_t*)(ws + OFF_QF))[u] = cvt_pk_bf16(q_w[o * 128 + k], q_w[o * 128 + k + 1]);
  } else {
    int u = tid - 548864;
    int jp = u & 3, l = (u >> 2) & 63, nt = (u >> 8) & 3, ks = u >> 10;
    int k = ks * 16 + (l >> 5) * 8 + jp * 2;
    int o = nt * 32 + (l & 31);
    ((uint32_t*)(ws + OFF_PF))[u] = cvt_pk_bf16(proj_w[o * 128 + k], proj_w[o * 128 + k + 1]);
  }
}

// Conv split-K (verbatim rounds 8/11/12, validated incl. NSUB=1).
template<int NSUB>
__global__ __launch_bounds__(512, 2) void conv_partial(
    const float* __restrict__ x, const uint32_t* __restrict__ cf,
    float* __restrict__ partial) {
  extern __shared__ __align__(16) char lds[];
  const int t = threadIdx.x;
  const int l = t & 63, w = t >> 6;
  const int NQ = 8 / NSUB;
  const int tile = blockIdx.x / NQ;
  const int khq  = blockIdx.x % NQ;
  const int b  = tile >> 4;
  const int ti = tile & 15;
  char* sreg = lds + w * 4096;
  const int col = l & 15, kg = (l >> 4) & 3;

  f32x4 acc[8];
  #pragma unroll
  for (int nt = 0; nt < 8; ++nt) acc[nt] = (f32x4)0.0f;

  #pragma unroll
  for (int si = 0; si < NSUB; ++si) {
    const int sub = khq * NSUB + si;
    #pragma unroll
    for (int it = 0; it < 4; ++it) {
      int flat = it * 64 + l;
      int tk = flat >> 4, c16 = flat & 15;
      const float* src = x + ((size_t)b * NN + ((ti * 8 + w) * 128 + tk * 8 + sub)) * CC + c16 * 8;
      float4 a0 = *(const float4*)(src);
      float4 a1 = *(const float4*)(src + 4);
      U4 pk;
      pk.u[0] = cvt_pk_bf16(a0.x, a0.y); pk.u[1] = cvt_pk_bf16(a0.z, a0.w);
      pk.u[2] = cvt_pk_bf16(a1.x, a1.y); pk.u[3] = cvt_pk_bf16(a1.z, a1.w);
      *(uint4*)(sreg + tk * 256 + ((c16 * 16) ^ ((tk & 7) << 4))) = pk.q;
    }
    const int ksg0 = (w * 8 + sub) * 4;
    #pragma unroll
    for (int ksl = 0; ksl < 4; ++ksl) {
      U4 a;
      a.q = *(const uint4*)(sreg + col * 256 + ((ksl * 64 + kg * 16) ^ ((col & 7) << 4)));
      #pragma unroll
      for (int nt = 0; nt < 8; ++nt) {
        U4 bf_;
        bf_.q = *(const uint4*)(cf + (((ksg0 + ksl) * 8 + nt) * 64 + l) * 4);
        acc[nt] = __builtin_amdgcn_mfma_f32_16x16x32_bf16(a.v, bf_.v, acc[nt], 0, 0, 0);
      }
    }
  }

  float* rbuf = (float*)(lds + 32768);
  if (w >= 4) {
    float* dst = rbuf + (w - 4) * 2048;
    #pragma unroll
    for (int nt = 0; nt < 8; ++nt)
      #pragma unroll
      for (int r = 0; r < 4; ++r) dst[(kg * 4 + r) * 128 + nt * 16 + col] = acc[nt][r];
  }
  __syncthreads();
  if (w < 4) {
    const float* s1 = rbuf + w * 2048;
    #pragma unroll
    for (int nt = 0; nt < 8; ++nt)
      #pragma unroll
      for (int r = 0; r < 4; ++r) acc[nt][r] += s1[(kg * 4 + r) * 128 + nt * 16 + col];
    if (w >= 2) {
      float* dst = rbuf + w * 2048;
      #pragma unroll
      for (int nt = 0; nt < 8; ++nt)
        #pragma unroll
        for (int r = 0; r < 4; ++r) dst[(kg * 4 + r) * 128 + nt * 16 + col] = acc[nt][r];
    }
  }
  __syncthreads();
  if (w < 2) {
    const float* s2 = rbuf + (w + 2) * 2048;
    #pragma unroll
    for (int nt = 0; nt < 8; ++nt)
      #pragma unroll
      for (int r = 0; r < 4; ++r) acc[nt][r] += s2[(kg * 4 + r) * 128 + nt * 16 + col];
    if (w == 1) {
      float* dst = rbuf + 2048;
      #pragma unroll
      for (int nt = 0; nt < 8; ++nt)
        #pragma unroll
        for (int r = 0; r < 4; ++r) dst[(kg * 4 + r) * 128 + nt * 16 + col] = acc[nt][r];
    }
  }
  __syncthreads();
  if (w == 0) {
    const float* s3 = rbuf + 2048;
    #pragma unroll
    for (int nt = 0; nt < 8; ++nt)
      #pragma unroll
      for (int r = 0; r < 4; ++r) {
        acc[nt][r] += s3[(kg * 4 + r) * 128 + nt * 16 + col];
        rbuf[(kg * 4 + r) * 128 + nt * 16 + col] = acc[nt][r];
      }
  }
  __syncthreads();
  float4 vv = ((const float4*)rbuf)[t];
  ((float4*)(partial + ((size_t)khq * 128 + tile) * 2048))[t] = vv;
}

// Reduce + LN + KV proj (verbatim round 8, validated).
__global__ __launch_bounds__(512) void reduce_ln_kv(
    const float* __restrict__ partial, int nq,
    const uint32_t* __restrict__ kvf, const float* __restrict__ kv_b,
    const float* __restrict__ ln_g, const float* __restrict__ ln_b,
    float* __restrict__ kbuf, float* __restrict__ vbuf) {
  __shared__ __align__(16) char abuf[4096];
  const int t = threadIdx.x;
  const int l = t & 63, w = t >> 6;
  const int tile = blockIdx.x;
  const int b = tile >> 4, nk0 = (tile & 15) * 16;

  float4 a = make_float4(0.f, 0.f, 0.f, 0.f);
  for (int i = 0; i < nq; ++i) {
    float4 p = *(const float4*)(partial + ((size_t)i * 128 + tile) * 2048 + t * 4);
    a.x += p.x; a.y += p.y; a.z += p.z; a.w += p.w;
  }
  {
    const int tk = t >> 5, j = t & 31;
    float s  = a.x + a.y + a.z + a.w;
    float ss = a.x * a.x + a.y * a.y + a.z * a.z + a.w * a.w;
    #pragma unroll
    for (int m = 16; m; m >>= 1) { s += __shfl_xor(s, m); ss += __shfl_xor(ss, m); }
    float mu  = s * 0.0078125f;
    float var = fmaxf(ss * 0.0078125f - mu * mu, 0.f);
    float rs  = rsqrtf(var + 1e-5f);
    float4 g4 = *(const float4*)(ln_g + j * 4);
    float4 b4 = *(const float4*)(ln_b + j * 4);
    float y0 = (a.x - mu) * rs * g4.x + b4.x;
    float y1 = (a.y - mu) * rs * g4.y + b4.y;
    float y2 = (a.z - mu) * rs * g4.z + b4.z;
    float y3 = (a.w - mu) * rs * g4.w + b4.w;
    *(uint2*)(abuf + tk * 256 + ((j * 8) ^ ((tk & 7) << 4))) =
        make_uint2(cvt_pk_bf16(y0, y1), cvt_pk_bf16(y2, y3));
  }
  __syncthreads();

  const int col = l & 15, kg = (l >> 4) & 3;
  f32x4 kacc[2];
  kacc[0] = (f32x4)0.0f; kacc[1] = (f32x4)0.0f;
  #pragma unroll
  for (int ks = 0; ks < 4; ++ks) {
    U4 aa;
    aa.q = *(const uint4*)(abuf + col * 256 + ((ks * 64 + kg * 16) ^ ((col & 7) << 4)));
    #pragma unroll
    for (int i = 0; i < 2; ++i) {
      int nt = w * 2 + i;
      U4 bf_;
      bf_.q = *(const uint4*)(kvf + ((ks * 16 + nt) * 64 + l) * 4);
      kacc[i] = __builtin_amdgcn_mfma_f32_16x16x32_bf16(aa.v, bf_.v, kacc[i], 0, 0, 0);
    }
  }
  #pragma unroll
  for (int i = 0; i < 2; ++i) {
    int kvo = (w * 2 + i) * 16 + col;
    float bias = kv_b[kvo];
    float* obuf = (kvo >= 128) ? vbuf : kbuf;
    int h = (kvo >> 6) & 1, d = kvo & 63;
    #pragma unroll
    for (int r = 0; r < 4; ++r) {
      int tkr = kg * 4 + r;
      obuf[(((size_t)b * HEADS + h) * NK + nk0 + tkr) * HD + d] = kacc[i][r] + bias;
    }
  }
}

// Thin MFMA GEMM (verbatim rounds 2-12, validated).
__global__ __launch_bounds__(256) void gemm128(
    const float* X, const uint32_t* __restrict__ frags,
    const float* __restrict__ bias, float scale, float* Y) {
  const int t = threadIdx.x;
  const int l = t & 63, wid = t >> 6;
  const int lq = l & 31, lh = l >> 5;
  const size_t rowbase = (size_t)blockIdx.x * 128 + wid * 32;
  const float* xrow = X + (rowbase + lq) * CC;
  f32x16 acc[4];
  #pragma unroll
  for (int nt = 0; nt < 4; ++nt) acc[nt] = (f32x16)0.0f;
  #pragma unroll
  for (int ks = 0; ks < 8; ++ks) {
    float4 a0 = *(const float4*)(xrow + ks * 16 + lh * 8);
    float4 a1 = *(const float4*)(xrow + ks * 16 + lh * 8 + 4);
    U4 af;
    af.u[0] = cvt_pk_bf16(a0.x, a0.y); af.u[1] = cvt_pk_bf16(a0.z, a0.w);
    af.u[2] = cvt_pk_bf16(a1.x, a1.y); af.u[3] = cvt_pk_bf16(a1.z, a1.w);
    #pragma unroll
    for (int nt = 0; nt < 4; ++nt) {
      U4 bf_;
      bf_.q = *(const uint4*)(frags + ((ks * 4 + nt) * 64 + l) * 4);
      acc[nt] = __builtin_amdgcn_mfma_f32_32x32x16_bf16(af.v, bf_.v, acc[nt], 0, 0, 0);
    }
  }
  #pragma unroll
  for (int nt = 0; nt < 4; ++nt) {
    int o = nt * 32 + lq;
    float bv = bias[o];
    #pragma unroll
    for (int r = 0; r < 16; ++r) {
      int m = (r & 3) + 8 * (r >> 2) + 4 * lh;
      Y[(rowbase + m) * CC + o] = (acc[nt][r] + bv) * scale;
    }
  }
}

// MFMA attention (verbatim round 8, validated, 47us): 64KB LDS, K+V staged
// together before compute (one barrier). 2048 blocks x 256 thr (4 waves).
// Register-bound at 2 waves/SIMD (p[8]=128 regs) — 32KB split-stage variant
// (R12) was slower (59us): same occupancy, extra serial V-load phase.
__global__ __launch_bounds__(256, 2) void attn_mfma(
    const float* __restrict__ qsrc, const float* __restrict__ kbuf,
    const float* __restrict__ vbuf, float* __restrict__ out) {
  __shared__ __align__(16) char lds[65536];  // [0,32K) K bf16 swz; [32K,64K) V^T bf16 swz
  const int t  = threadIdx.x;
  const int l  = t & 63, wid = t >> 6;
  const int lq = l & 31, lh = l >> 5;
  const int bh = blockIdx.x >> 7;
  const int b  = bh >> 1, h = bh & 1;
  const int qbase = (blockIdx.x & 127) * 128;

  // ---- Phase A: Q B-frags straight from global fp32 ----
  U4 qb[4];
  {
    const float* q0 = qsrc + ((size_t)b * NN + qbase + wid * 32 + lq) * CC + h * 64;
    #pragma unroll
    for (int kg = 0; kg < 4; ++kg) {
      float4 x0 = *(const float4*)(q0 + kg * 16 + lh * 8);
      float4 x1 = *(const float4*)(q0 + kg * 16 + lh * 8 + 4);
      qb[kg].u[0] = cvt_pk_bf16(x0.x, x0.y); qb[kg].u[1] = cvt_pk_bf16(x0.z, x0.w);
      qb[kg].u[2] = cvt_pk_bf16(x1.x, x1.y); qb[kg].u[3] = cvt_pk_bf16(x1.z, x1.w);
    }
  }

  // ---- Phase B: stage K [256][64] and V^T [64][256] as swizzled bf16 ----
  {
    const float* kb = kbuf + (size_t)bh * NK * HD;
    #pragma unroll
    for (int it = 0; it < 16; ++it) {
      int flat = it * 256 + t;
      int key = flat >> 4, j = flat & 15;
      float4 kv = *(const float4*)(kb + key * HD + j * 4);
      int byte = (key * 128 + j * 8) ^ ((key & 7) << 4);
      *(uint2*)(lds + byte) = make_uint2(cvt_pk_bf16(kv.x, kv.y), cvt_pk_bf16(kv.z, kv.w));
    }
    const float* vb = vbuf + (size_t)bh * NK * HD;
    int d = t & 63, kb4 = t >> 6;
    #pragma unroll
    for (int k0 = 0; k0 < 64; k0 += 4) {
      int k = kb4 * 64 + k0;
      float v0 = vb[(k + 0) * HD + d], v1 = vb[(k + 1) * HD + d];
      float v2 = vb[(k + 2) * HD + d], v3 = vb[(k + 3) * HD + d];
      int byte = 32768 + ((d * 512 + k * 2) ^ ((d & 7) << 4));
      *(uint2*)(lds + byte) = make_uint2(cvt_pk_bf16(v0, v1), cvt_pk_bf16(v2, v3));
    }
  }
  __syncthreads();

  // ---- Phase C: S^T = K · Q^T ----
  f32x16 p[8];
  #pragma unroll
  for (int kt = 0; kt < 8; ++kt) p[kt] = (f32x16)0.0f;
  #pragma unroll
  for (int kt = 0; kt < 8; ++kt) {
    const int key = kt * 32 + lq;
    #pragma unroll
    for (int kg = 0; kg < 4; ++kg) {
      U4 a;
      int byte = (key * 128 + kg * 32 + lh * 16) ^ ((key & 7) << 4);
      a.q = *(const uint4*)(lds + byte);
      p[kt] = __builtin_amdgcn_mfma_f32_32x32x16_bf16(a.v, qb[kg].v, p[kt], 0, 0, 0);
    }
  }

  // ---- Phase D: softmax ----
  float mx = -1e30f;
  #pragma unroll
  for (int kt = 0; kt < 8; ++kt)
    #pragma unroll
    for (int i = 0; i < 16; ++i) mx = fmaxf(mx, p[kt][i]);
  mx = fmaxf(mx, __shfl_xor(mx, 32));
  float sum = 0.f;
  #pragma unroll
  for (int kt = 0; kt < 8; ++kt)
    #pragma unroll
    for (int i = 0; i < 16; ++i) { float e = __expf(p[kt][i] - mx); p[kt][i] = e; sum += e; }
  sum += __shfl_xor(sum, 32);
  const float inv = 1.f / sum;
  #pragma unroll
  for (int kt = 0; kt < 8; ++kt)
    #pragma unroll
    for (int i = 0; i < 16; ++i) p[kt][i] *= inv;

  // ---- Phase E: O = P · V ----
  f32x16 oacc0 = (f32x16)0.0f, oacc1 = (f32x16)0.0f;
  #pragma unroll
  for (int kt = 0; kt < 8; ++kt) {
    uint32_t x0 = cvt_pk_bf16(p[kt][0],  p[kt][1]);
    uint32_t x1 = cvt_pk_bf16(p[kt][2],  p[kt][3]);
    uint32_t y0 = cvt_pk_bf16(p[kt][4],  p[kt][5]);
    uint32_t y1 = cvt_pk_bf16(p[kt][6],  p[kt][7]);
    permswap(x0, y0); permswap(x1, y1);
    U4 pa0; pa0.u[0] = x0; pa0.u[1] = x1; pa0.u[2] = y0; pa0.u[3] = y1;
    uint32_t x2 = cvt_pk_bf16(p[kt][8],  p[kt][9]);
    uint32_t x3 = cvt_pk_bf16(p[kt][10], p[kt][11]);
    uint32_t y2 = cvt_pk_bf16(p[kt][12], p[kt][13]);
    uint32_t y3 = cvt_pk_bf16(p[kt][14], p[kt][15]);
    permswap(x2, y2); permswap(x3, y3);
    U4 pa1; pa1.u[0] = x2; pa1.u[1] = x3; pa1.u[2] = y2; pa1.u[3] = y3;
    #pragma unroll
    for (int dt = 0; dt < 2; ++dt) {
      int d = dt * 32 + lq;
      U4 vb0, vb1;
      int byte0 = 32768 + ((d * 512 + kt * 64 + lh * 16) ^ ((d & 7) << 4));
      int byte1 = 32768 + ((d * 512 + kt * 64 + 32 + lh * 16) ^ ((d & 7) << 4));
      vb0.q = *(const uint4*)(lds + byte0);
      vb1.q = *(const uint4*)(lds + byte1);
      f32x16& oa = dt ? oacc1 : oacc0;
      oa = __builtin_amdgcn_mfma_f32_32x32x16_bf16(pa0.v, vb0.v, oa, 0, 0, 0);
      oa = __builtin_amdgcn_mfma_f32_32x32x16_bf16(pa1.v, vb1.v, oa, 0, 0, 0);
    }
  }

  // ---- Phase F: coalesced store (overwrites this block's own Q region) ----
  float* ob = out + ((size_t)b * NN + qbase + wid * 32) * CC + h * 64;
  #pragma unroll
  for (int reg = 0; reg < 16; ++reg) {
    int q = (reg & 3) + 8 * (reg >> 2) + 4 * lh;
    ob[q * CC + lq]      = oacc0[reg];
    ob[q * CC + 32 + lq] = oacc1[reg];
  }
}

extern "C" void kernel_launch(void* const* d_in, const int* in_sizes, int n_in,
                              void* d_out, int out_size, void* d_ws, size_t ws_size,
                              hipStream_t stream) {
  const float* x      = (const float*)d_in[0];
  const float* q_w    = (const float*)d_in[3];
  const float* q_b    = (const float*)d_in[4];
  const float* kv_w   = (const float*)d_in[5];
  const float* kv_b   = (const float*)d_in[6];
  const float* sr_w   = (const float*)d_in[7];
  const float* ln_g   = (const float*)d_in[8];
  const float* ln_b   = (const float*)d_in[9];
  const float* proj_w = (const float*)d_in[10];
  const float* proj_b = (const float*)d_in[11];
  float* out = (float*)d_out;
  float* ws  = (float*)d_ws;

  prep_w<<<dim3(2176), dim3(256), 0, stream>>>(sr_w, proj_w, kv_w, q_w, ws);

  int nq = 1;
  if (ws_size >= (size_t)(OFF_PART + 8 * 262144) * 4) nq = 8;
  else if (ws_size >= (size_t)(OFF_PART + 4 * 262144) * 4) nq = 4;
  else if (ws_size >= (size_t)(OFF_PART + 2 * 262144) * 4) nq = 2;

  const uint32_t* cf = (const uint32_t*)(ws + OFF_CF);
  float* part = ws + OFF_PART;
  if (nq == 8)
    conv_partial<1><<<dim3(1024), dim3(512), 65536, stream>>>(x, cf, part);
  else if (nq == 4)
    conv_partial<2><<<dim3(512), dim3(512), 65536, stream>>>(x, cf, part);
  else if (nq == 2)
    conv_partial<4><<<dim3(256), dim3(512), 65536, stream>>>(x, cf, part);
  else
    conv_partial<8><<<dim3(128), dim3(512), 65536, stream>>>(x, cf, part);

  reduce_ln_kv<<<dim3(128), dim3(512), 0, stream>>>(
      part, nq, (const uint32_t*)(ws + OFF_KVF), kv_b, ln_g, ln_b,
      ws + OFF_K, ws + OFF_V);
  gemm128<<<dim3(1024), dim3(256), 0, stream>>>(
      x, (const uint32_t*)(ws + OFF_QF), q_b, 0.125f, out);
  attn_mfma<<<dim3(2048), dim3(256), 0, stream>>>(
      out, ws + OFF_K, ws + OFF_V, out);
  gemm128<<<dim3(1024), dim3(256), 0, stream>>>(
      out, (const uint32_t*)(ws + OFF_PF), proj_b, 1.0f, out);
}